// Round 4
// baseline (831.976 us; speedup 1.0000x reference)
//
#include <hip/hip_runtime.h>
#include <hip/hip_fp16.h>
#include <math.h>

#define SCALE 0.4082482904638631f   // 1/sqrt(6)

#define BATCH 8
#define HW    256
#define NPIX  65536

// ---------------- workspace layout ----------------
#define QKV_H_SIZE ((size_t)BATCH*144*NPIX)        // halves
#define VP_H_SIZE  ((size_t)BATCH*48*NPIX)         // halves
#define F_BYTE_OFF ((QKV_H_SIZE + VP_H_SIZE) * 2)  // byte offset of float region
#define GP_SIZE    (BATCH*32*8*48)                 // 98304 floats
#define M_SIZE     (BATCH*48*48)                   // 18432 floats
// float region: [gp][Mmat][w1t]

struct __align__(16) H8 { __half h[8]; };

// ===========================================================================
// K_t: transpose w1 (144x48) -> w1t (48x144) so ka's weight reads are wide
// consecutive uniform s_loads.
// ===========================================================================
__global__ void kt_w1t(const float* __restrict__ w1, float* __restrict__ w1t)
{
  for (int i = threadIdx.x; i < 144 * 48; i += 256) {
    const int ic = i / 144, oc = i - ic * 144;
    w1t[i] = w1[oc * 48 + ic];
  }
}

// ===========================================================================
// K_a: 1x1 conv (48 -> 144), fp32 in, fp16 out. Streaming-ic structure:
// 72 live accumulators (x2 passes) force the values to stay in VGPRs —
// x is loaded exactly 96x/thread (coalesced), weights are uniform s_loads.
// ===========================================================================
__global__ __launch_bounds__(256, 4) void ka_conv1(
    const float* __restrict__ x, const float* __restrict__ w1t,
    __half* __restrict__ qkv)
{
  const int g = blockIdx.x * 256 + threadIdx.x;
  const int b = g >> 16;
  const int n = g & 65535;
  const float* xb = x + ((size_t)b * 48) * NPIX + n;
  __half* ob = qkv + ((size_t)b * 144) * NPIX + n;

#pragma unroll 1
  for (int pass = 0; pass < 2; ++pass) {
    const int oc0 = pass * 72;
    float acc[72];
#pragma unroll
    for (int j = 0; j < 72; ++j) acc[j] = 0.0f;
    float xr = xb[0];
#pragma unroll 1
    for (int ic = 0; ic < 48; ++ic) {
      const int icn = (ic < 47) ? ic + 1 : 47;
      const float xn = xb[(size_t)icn * NPIX];         // prefetch next
      const float* wrow = w1t + ic * 144 + oc0;
#pragma unroll
      for (int j = 0; j < 72; ++j) acc[j] = fmaf(wrow[j], xr, acc[j]);
      xr = xn;
    }
#pragma unroll
    for (int j = 0; j < 72; ++j)
      ob[(size_t)(oc0 + j) * NPIX] = __float2half(acc[j]);
  }
}

// ===========================================================================
// K_b_qk: per (b, head, 8-row band): stage 12 q/k channels x 10 rows x 256
// cols (fp16) in LDS via aligned dwordx4; dw-conv from LDS (H8 + 2 edge u16
// per row window); accumulate 48 gram values; block-reduce -> gram_part.
// LDS 63360 B -> 2 blocks/CU. Thread = 8 cols x 1 row (g=tid&31, rl=tid>>5).
// ===========================================================================
__global__ __launch_bounds__(256, 2) void kb_qk(
    const __half* __restrict__ qkv, const float* __restrict__ wd,
    float* __restrict__ gram_part)
{
  __shared__ __align__(16) unsigned char smem[63360];
  __half* st  = (__half*)smem;               // [12][10][264]
  float*  red = (float*)smem;                // [256][52]  (aliased, after sync)
  float*  pr  = (float*)(smem + 53248);      // [192]

  const int blk  = blockIdx.x;
  const int band = blk & 31;
  const int h    = (blk >> 5) & 7;
  const int b    = blk >> 8;
  const int y0   = band * 8;
  const int tid  = threadIdx.x;
  const int g    = tid & 31;                 // col group (8 cols)
  const int rl   = tid >> 5;                 // out row 0..7
  const int x0   = g * 8;

  // ---- stage 12 channels x 10 rows ----
  const __half* qb = qkv + ((size_t)b * 144) * NPIX;
#pragma unroll
  for (int j = 0; j < 15; ++j) {
    const int cid = tid + j * 256;           // 0..3839
    const int ch  = cid / 320;
    const int rem = cid - ch * 320;
    const int r   = rem >> 5;
    const int c16 = rem & 31;
    const int gch = (ch < 6) ? (6 * h + ch) : (42 + 6 * h + ch);
    const int grow = y0 - 1 + r;
    H8 v;
    if ((unsigned)grow < 256u) {
      v = *(const H8*)(qb + (size_t)gch * NPIX + grow * 256 + c16 * 8);
    } else {
#pragma unroll
      for (int q = 0; q < 8; ++q) v.h[q] = __float2half(0.0f);
    }
    *(H8*)(st + (ch * 10 + r) * 264 + c16 * 8) = v;
  }
  __syncthreads();

  // ---- dw conv + gram ----
  auto dwrow = [&](int chslot, int gch, float o[8]) {
    const float* w9 = wd + gch * 9;
#pragma unroll
    for (int p = 0; p < 8; ++p) o[p] = 0.0f;
#pragma unroll
    for (int dr = 0; dr < 3; ++dr) {
      const __half* rowp = st + (chslot * 10 + rl + dr) * 264;
      float wn[10];
      wn[0] = (g > 0) ? __half2float(rowp[x0 - 1]) : 0.0f;
      const H8 m = *(const H8*)(rowp + x0);
#pragma unroll
      for (int q = 0; q < 8; ++q) wn[q + 1] = __half2float(m.h[q]);
      wn[9] = (g < 31) ? __half2float(rowp[x0 + 8]) : 0.0f;
#pragma unroll
      for (int dx = 0; dx < 3; ++dx) {
        const float wt = w9[dr * 3 + dx];
#pragma unroll
        for (int p = 0; p < 8; ++p) o[p] = fmaf(wt, wn[p + dx], o[p]);
      }
    }
  };

  float gram[48];
  float qv[6][8];
#pragma unroll
  for (int d = 0; d < 6; ++d) {
    dwrow(d, 6 * h + d, qv[d]);
    float s = 0.0f;
#pragma unroll
    for (int p = 0; p < 8; ++p) s = fmaf(qv[d][p], qv[d][p], s);
    gram[d] = s;
  }
#pragma unroll
  for (int e = 0; e < 6; ++e) {
    float kv[8];
    dwrow(6 + e, 48 + 6 * h + e, kv);
    float s = 0.0f;
#pragma unroll
    for (int p = 0; p < 8; ++p) s = fmaf(kv[p], kv[p], s);
    gram[6 + e] = s;
#pragma unroll
    for (int d = 0; d < 6; ++d) {
      float t = 0.0f;
#pragma unroll
      for (int p = 0; p < 8; ++p) t = fmaf(qv[d][p], kv[p], t);
      gram[12 + 6 * d + e] = t;
    }
  }
  __syncthreads();   // staging reads done; reuse smem as red

  float4* wrow4 = (float4*)(red + tid * 52);
#pragma unroll
  for (int j = 0; j < 12; ++j)
    wrow4[j] = make_float4(gram[4 * j], gram[4 * j + 1], gram[4 * j + 2], gram[4 * j + 3]);
  __syncthreads();

  if (tid < 192) {
    const int vv = tid >> 2, ch = tid & 3;
    float s = 0.0f;
    const float* base = red + (ch * 64) * 52 + vv;
    for (int p = 0; p < 64; ++p) s += base[p * 52];
    pr[vv * 4 + ch] = s;
  }
  __syncthreads();
  if (tid < 48)
    gram_part[(((size_t)b * 32 + band) * 8 + h) * 48 + tid] =
        pr[tid * 4] + pr[tid * 4 + 1] + pr[tid * 4 + 2] + pr[tid * 4 + 3];
}

// ===========================================================================
// K_b_v: per (b, v-channel, 32-row band): stage 34 rows x 256 cols fp16 in
// LDS; dw-conv from LDS; write fp16 v' (aligned 16-B stores).
// LDS 17952 B. Thread = 8 cols x 4 rows.
// ===========================================================================
__global__ __launch_bounds__(256) void kb_v(
    const __half* __restrict__ qkv, const float* __restrict__ wd,
    __half* __restrict__ vp_ws)
{
  __shared__ __align__(16) __half st[34 * 264];

  const int blk  = blockIdx.x;
  const int band = blk & 7;
  const int ch   = (blk >> 3) % 48;
  const int b    = blk / (48 * 8);
  const int y0   = band * 32;
  const int tid  = threadIdx.x;
  const int g    = tid & 31;
  const int rl   = tid >> 5;
  const int x0   = g * 8;
  const int gch  = 96 + ch;

  const __half* plane = qkv + ((size_t)b * 144 + gch) * NPIX;
#pragma unroll
  for (int j = 0; j < 5; ++j) {
    const int cid = tid + j * 256;           // 0..1087
    if (cid < 1088) {
      const int r   = cid >> 5;
      const int c16 = cid & 31;
      const int grow = y0 - 1 + r;
      H8 v;
      if ((unsigned)grow < 256u) {
        v = *(const H8*)(plane + grow * 256 + c16 * 8);
      } else {
#pragma unroll
        for (int q = 0; q < 8; ++q) v.h[q] = __float2half(0.0f);
      }
      *(H8*)(st + r * 264 + c16 * 8) = v;
    }
  }
  __syncthreads();

  const float* w9 = wd + gch * 9;
  __half* outp = vp_ws + ((size_t)b * 48 + ch) * NPIX;
#pragma unroll
  for (int i = 0; i < 4; ++i) {
    const int r_out = rl + 8 * i;
    float o[8];
#pragma unroll
    for (int p = 0; p < 8; ++p) o[p] = 0.0f;
#pragma unroll
    for (int dr = 0; dr < 3; ++dr) {
      const __half* rowp = st + (r_out + dr) * 264;
      float wn[10];
      wn[0] = (g > 0) ? __half2float(rowp[x0 - 1]) : 0.0f;
      const H8 m = *(const H8*)(rowp + x0);
#pragma unroll
      for (int q = 0; q < 8; ++q) wn[q + 1] = __half2float(m.h[q]);
      wn[9] = (g < 31) ? __half2float(rowp[x0 + 8]) : 0.0f;
#pragma unroll
      for (int dx = 0; dx < 3; ++dx) {
        const float wt = w9[dr * 3 + dx];
#pragma unroll
        for (int p = 0; p < 8; ++p) o[p] = fmaf(wt, wn[p + dx], o[p]);
      }
    }
    H8 hv;
#pragma unroll
    for (int p = 0; p < 8; ++p) hv.h[p] = __float2half(o[p]);
    *(H8*)(outp + (y0 + r_out) * 256 + x0) = hv;
  }
}

// ===========================================================================
// K_d: per (b,head): sum 32 band partials -> norms -> softmax -> fold W_proj
// ===========================================================================
__global__ void kd_attn(const float* __restrict__ gram_part,
                        const float* __restrict__ wp, float* __restrict__ Mmat)
{
  const int b = blockIdx.x >> 3;
  const int h = blockIdx.x & 7;
  __shared__ float S[48];
  __shared__ float attn[36];
  const int tid = threadIdx.x;   // 64 threads

  if (tid < 48) {
    float s = 0.0f;
    for (int t = 0; t < 32; ++t)
      s += gram_part[(((size_t)b * 32 + t) * 8 + h) * 48 + tid];
    S[tid] = s;
  }
  __syncthreads();
  if (tid < 36) {
    const int d = tid / 6, e = tid - 6 * d;
    const float nq = fmaxf(sqrtf(S[d]),     1e-12f);
    const float nk = fmaxf(sqrtf(S[6 + e]), 1e-12f);
    attn[tid] = S[12 + tid] / (nq * nk) * SCALE;
  }
  __syncthreads();
  if (tid < 6) {
    float m = attn[tid * 6];
    for (int e = 1; e < 6; ++e) m = fmaxf(m, attn[tid * 6 + e]);
    float ex[6]; float sum = 0.0f;
    for (int e = 0; e < 6; ++e) { ex[e] = expf(attn[tid * 6 + e] - m); sum += ex[e]; }
    const float inv = 1.0f / sum;
    for (int e = 0; e < 6; ++e) attn[tid * 6 + e] = ex[e] * inv;
  }
  __syncthreads();
  for (int i = tid; i < 288; i += 64) {
    const int c = i / 6, e = i - 6 * (i / 6);
    float s = 0.0f;
#pragma unroll
    for (int d = 0; d < 6; ++d) s += wp[c * 48 + 6 * h + d] * attn[d * 6 + e];
    Mmat[((size_t)b * 48 + c) * 48 + 6 * h + e] = s;
  }
}

// ===========================================================================
// K_e: y[b][c][n] = sum_{c'} M_b[c][c'] * v'[b][c'][n]; 2 px/thread,
// half2 loads / float2 stores.
// ===========================================================================
__global__ __launch_bounds__(256, 4) void ke_out(
    const __half* __restrict__ vp_ws, const float* __restrict__ Mmat,
    float* __restrict__ y)
{
  const int p = blockIdx.x * 256 + threadIdx.x;
  const int b = p >> 15;
  const int n = (p & 32767) * 2;
  const __half* vb = vp_ws + ((size_t)b * 48) * NPIX + n;
  const float* Mb = Mmat + (size_t)b * 2304;
  float vv[96];
#pragma unroll
  for (int c = 0; c < 48; ++c) {
    const float2 f = __half22float2(*(const __half2*)(vb + (size_t)c * NPIX));
    vv[2 * c] = f.x; vv[2 * c + 1] = f.y;
  }
  float* yb = y + ((size_t)b * 48) * NPIX + n;
#pragma unroll 2
  for (int c = 0; c < 48; ++c) {
    float s0 = 0.0f, s1 = 0.0f;
#pragma unroll
    for (int cc = 0; cc < 48; ++cc) {
      const float w = Mb[c * 48 + cc];
      s0 = fmaf(w, vv[2 * cc], s0);
      s1 = fmaf(w, vv[2 * cc + 1], s1);
    }
    *(float2*)(yb + (size_t)c * NPIX) = make_float2(s0, s1);
  }
}

// ===========================================================================
extern "C" void kernel_launch(void* const* d_in, const int* in_sizes, int n_in,
                              void* d_out, int out_size, void* d_ws, size_t ws_size,
                              hipStream_t stream)
{
  const float* x  = (const float*)d_in[0];
  const float* w1 = (const float*)d_in[1];   // (144,48,1,1)
  const float* wd = (const float*)d_in[2];   // (144,1,3,3)
  const float* wp = (const float*)d_in[3];   // (48,48,1,1)

  __half* qkv = (__half*)d_ws;
  __half* vp  = qkv + QKV_H_SIZE;
  float*  fw  = (float*)((char*)d_ws + F_BYTE_OFF);
  float*  gp   = fw;
  float*  Mmat = fw + GP_SIZE;
  float*  w1t  = Mmat + M_SIZE;

  hipLaunchKernelGGL(kt_w1t,   dim3(1),    dim3(256), 0, stream, w1, w1t);
  hipLaunchKernelGGL(ka_conv1, dim3(2048), dim3(256), 0, stream, x, w1t, qkv);
  hipLaunchKernelGGL(kb_qk,    dim3(2048), dim3(256), 0, stream, qkv, wd, gp);
  hipLaunchKernelGGL(kb_v,     dim3(3072), dim3(256), 0, stream, qkv, wd, vp);
  hipLaunchKernelGGL(kd_attn,  dim3(64),   dim3(64),  0, stream, gp, wp, Mmat);
  hipLaunchKernelGGL(ke_out,   dim3(1024), dim3(256), 0, stream, vp, Mmat, (float*)d_out);
}

// Round 5
// 406.454 us; speedup vs baseline: 2.0469x; 2.0469x over previous
//
#include <hip/hip_runtime.h>
#include <hip/hip_fp16.h>
#include <math.h>

#define SCALE 0.4082482904638631f   // 1/sqrt(6)

#define BATCH 8
#define HW    256
#define NPIX  65536

// ---------------- workspace layout ----------------
#define QKV_H_SIZE ((size_t)BATCH*144*NPIX)        // halves
#define VP_H_SIZE  ((size_t)BATCH*48*NPIX)         // halves
#define F_BYTE_OFF ((QKV_H_SIZE + VP_H_SIZE) * 2)  // byte offset of float region
#define GP_SIZE    (BATCH*32*8*48)                 // 98304 floats
#define M_SIZE     (BATCH*48*48)                   // 18432 floats
// float region: [gp][Mmat][w1t]

struct __align__(16) H8 { __half h[8]; };

// ===========================================================================
// K_t: transpose w1 (144x48) -> w1t (48x144) so ka's weight reads are wide
// consecutive uniform s_loads.
// ===========================================================================
__global__ void kt_w1t(const float* __restrict__ w1, float* __restrict__ w1t)
{
  for (int i = threadIdx.x; i < 144 * 48; i += 256) {
    const int ic = i / 144, oc = i - ic * 144;
    w1t[i] = w1[oc * 48 + ic];
  }
}

// ===========================================================================
// K_a: 1x1 conv (48 -> 144), fp32 in, fp16 out. Streaming-ic structure:
// 72 live accumulators (x2 passes); x loaded 96x/thread coalesced; weights
// uniform s_loads.
// ===========================================================================
__global__ __launch_bounds__(256, 4) void ka_conv1(
    const float* __restrict__ x, const float* __restrict__ w1t,
    __half* __restrict__ qkv)
{
  const int g = blockIdx.x * 256 + threadIdx.x;
  const int b = g >> 16;
  const int n = g & 65535;
  const float* xb = x + ((size_t)b * 48) * NPIX + n;
  __half* ob = qkv + ((size_t)b * 144) * NPIX + n;

#pragma unroll 1
  for (int pass = 0; pass < 2; ++pass) {
    const int oc0 = pass * 72;
    float acc[72];
#pragma unroll
    for (int j = 0; j < 72; ++j) acc[j] = 0.0f;
    float xr = xb[0];
#pragma unroll 1
    for (int ic = 0; ic < 48; ++ic) {
      const int icn = (ic < 47) ? ic + 1 : 47;
      const float xn = xb[(size_t)icn * NPIX];         // prefetch next
      const float* wrow = w1t + ic * 144 + oc0;
#pragma unroll
      for (int j = 0; j < 72; ++j) acc[j] = fmaf(wrow[j], xr, acc[j]);
      xr = xn;
    }
#pragma unroll
    for (int j = 0; j < 72; ++j)
      ob[(size_t)(oc0 + j) * NPIX] = __float2half(acc[j]);
  }
}

// ===========================================================================
// K_b_qk: per (b, head, 8-row band): stage 12 q/k channels x 10 rows x 256
// cols (fp16) in LDS via aligned dwordx4; dw-conv from LDS; accumulate 48
// gram values; block-reduce -> gram_part. LDS 63360 B -> 2 blocks/CU.
// ===========================================================================
__global__ __launch_bounds__(256, 2) void kb_qk(
    const __half* __restrict__ qkv, const float* __restrict__ wd,
    float* __restrict__ gram_part)
{
  __shared__ __align__(16) unsigned char smem[63360];
  __half* st  = (__half*)smem;               // [12][10][264]
  float*  red = (float*)smem;                // [256][52]  (aliased, after sync)
  float*  pr  = (float*)(smem + 53248);      // [192]

  const int blk  = blockIdx.x;
  const int band = blk & 31;
  const int h    = (blk >> 5) & 7;
  const int b    = blk >> 8;
  const int y0   = band * 8;
  const int tid  = threadIdx.x;
  const int g    = tid & 31;                 // col group (8 cols)
  const int rl   = tid >> 5;                 // out row 0..7
  const int x0   = g * 8;

  // ---- stage 12 channels x 10 rows ----
  const __half* qb = qkv + ((size_t)b * 144) * NPIX;
#pragma unroll
  for (int j = 0; j < 15; ++j) {
    const int cid = tid + j * 256;           // 0..3839
    const int ch  = cid / 320;
    const int rem = cid - ch * 320;
    const int r   = rem >> 5;
    const int c16 = rem & 31;
    const int gch = (ch < 6) ? (6 * h + ch) : (42 + 6 * h + ch);
    const int grow = y0 - 1 + r;
    H8 v;
    if ((unsigned)grow < 256u) {
      v = *(const H8*)(qb + (size_t)gch * NPIX + grow * 256 + c16 * 8);
    } else {
#pragma unroll
      for (int q = 0; q < 8; ++q) v.h[q] = __float2half(0.0f);
    }
    *(H8*)(st + (ch * 10 + r) * 264 + c16 * 8) = v;
  }
  __syncthreads();

  // ---- dw conv + gram ----
  auto dwrow = [&](int chslot, int gch, float o[8]) {
    const float* w9 = wd + gch * 9;
#pragma unroll
    for (int p = 0; p < 8; ++p) o[p] = 0.0f;
#pragma unroll
    for (int dr = 0; dr < 3; ++dr) {
      const __half* rowp = st + (chslot * 10 + rl + dr) * 264;
      float wn[10];
      wn[0] = (g > 0) ? __half2float(rowp[x0 - 1]) : 0.0f;
      const H8 m = *(const H8*)(rowp + x0);
#pragma unroll
      for (int q = 0; q < 8; ++q) wn[q + 1] = __half2float(m.h[q]);
      wn[9] = (g < 31) ? __half2float(rowp[x0 + 8]) : 0.0f;
#pragma unroll
      for (int dx = 0; dx < 3; ++dx) {
        const float wt = w9[dr * 3 + dx];
#pragma unroll
        for (int p = 0; p < 8; ++p) o[p] = fmaf(wt, wn[p + dx], o[p]);
      }
    }
  };

  float gram[48];
  float qv[6][8];
#pragma unroll
  for (int d = 0; d < 6; ++d) {
    dwrow(d, 6 * h + d, qv[d]);
    float s = 0.0f;
#pragma unroll
    for (int p = 0; p < 8; ++p) s = fmaf(qv[d][p], qv[d][p], s);
    gram[d] = s;
  }
#pragma unroll
  for (int e = 0; e < 6; ++e) {
    float kv[8];
    dwrow(6 + e, 48 + 6 * h + e, kv);
    float s = 0.0f;
#pragma unroll
    for (int p = 0; p < 8; ++p) s = fmaf(kv[p], kv[p], s);
    gram[6 + e] = s;
#pragma unroll
    for (int d = 0; d < 6; ++d) {
      float t = 0.0f;
#pragma unroll
      for (int p = 0; p < 8; ++p) t = fmaf(qv[d][p], kv[p], t);
      gram[12 + 6 * d + e] = t;
    }
  }
  __syncthreads();   // staging reads done; reuse smem as red

  float4* wrow4 = (float4*)(red + tid * 52);
#pragma unroll
  for (int j = 0; j < 12; ++j)
    wrow4[j] = make_float4(gram[4 * j], gram[4 * j + 1], gram[4 * j + 2], gram[4 * j + 3]);
  __syncthreads();

  if (tid < 192) {
    const int vv = tid >> 2, ch = tid & 3;
    float s = 0.0f;
    const float* base = red + (ch * 64) * 52 + vv;
    for (int p = 0; p < 64; ++p) s += base[p * 52];
    pr[vv * 4 + ch] = s;
  }
  __syncthreads();
  if (tid < 48)
    gram_part[(((size_t)b * 32 + band) * 8 + h) * 48 + tid] =
        pr[tid * 4] + pr[tid * 4 + 1] + pr[tid * 4 + 2] + pr[tid * 4 + 3];
}

// ===========================================================================
// K_b_v: per (b, v-channel, 32-row band): stage 34 rows x 256 cols fp16 in
// LDS; dw-conv from LDS; write fp16 v' (aligned 16-B stores).
// ===========================================================================
__global__ __launch_bounds__(256) void kb_v(
    const __half* __restrict__ qkv, const float* __restrict__ wd,
    __half* __restrict__ vp_ws)
{
  __shared__ __align__(16) __half st[34 * 264];

  const int blk  = blockIdx.x;
  const int band = blk & 7;
  const int ch   = (blk >> 3) % 48;
  const int b    = blk / (48 * 8);
  const int y0   = band * 32;
  const int tid  = threadIdx.x;
  const int g    = tid & 31;
  const int rl   = tid >> 5;
  const int x0   = g * 8;
  const int gch  = 96 + ch;

  const __half* plane = qkv + ((size_t)b * 144 + gch) * NPIX;
#pragma unroll
  for (int j = 0; j < 5; ++j) {
    const int cid = tid + j * 256;           // 0..1087
    if (cid < 1088) {
      const int r   = cid >> 5;
      const int c16 = cid & 31;
      const int grow = y0 - 1 + r;
      H8 v;
      if ((unsigned)grow < 256u) {
        v = *(const H8*)(plane + grow * 256 + c16 * 8);
      } else {
#pragma unroll
        for (int q = 0; q < 8; ++q) v.h[q] = __float2half(0.0f);
      }
      *(H8*)(st + r * 264 + c16 * 8) = v;
    }
  }
  __syncthreads();

  const float* w9 = wd + gch * 9;
  __half* outp = vp_ws + ((size_t)b * 48 + ch) * NPIX;
#pragma unroll
  for (int i = 0; i < 4; ++i) {
    const int r_out = rl + 8 * i;
    float o[8];
#pragma unroll
    for (int p = 0; p < 8; ++p) o[p] = 0.0f;
#pragma unroll
    for (int dr = 0; dr < 3; ++dr) {
      const __half* rowp = st + (r_out + dr) * 264;
      float wn[10];
      wn[0] = (g > 0) ? __half2float(rowp[x0 - 1]) : 0.0f;
      const H8 m = *(const H8*)(rowp + x0);
#pragma unroll
      for (int q = 0; q < 8; ++q) wn[q + 1] = __half2float(m.h[q]);
      wn[9] = (g < 31) ? __half2float(rowp[x0 + 8]) : 0.0f;
#pragma unroll
      for (int dx = 0; dx < 3; ++dx) {
        const float wt = w9[dr * 3 + dx];
#pragma unroll
        for (int p = 0; p < 8; ++p) o[p] = fmaf(wt, wn[p + dx], o[p]);
      }
    }
    H8 hv;
#pragma unroll
    for (int p = 0; p < 8; ++p) hv.h[p] = __float2half(o[p]);
    *(H8*)(outp + (y0 + r_out) * 256 + x0) = hv;
  }
}

// ===========================================================================
// K_d: per (b,head): sum 32 band partials -> norms -> softmax -> fold W_proj
// ===========================================================================
__global__ void kd_attn(const float* __restrict__ gram_part,
                        const float* __restrict__ wp, float* __restrict__ Mmat)
{
  const int b = blockIdx.x >> 3;
  const int h = blockIdx.x & 7;
  __shared__ float S[48];
  __shared__ float attn[36];
  const int tid = threadIdx.x;   // 64 threads

  if (tid < 48) {
    float s = 0.0f;
    for (int t = 0; t < 32; ++t)
      s += gram_part[(((size_t)b * 32 + t) * 8 + h) * 48 + tid];
    S[tid] = s;
  }
  __syncthreads();
  if (tid < 36) {
    const int d = tid / 6, e = tid - 6 * d;
    const float nq = fmaxf(sqrtf(S[d]),     1e-12f);
    const float nk = fmaxf(sqrtf(S[6 + e]), 1e-12f);
    attn[tid] = S[12 + tid] / (nq * nk) * SCALE;
  }
  __syncthreads();
  if (tid < 6) {
    float m = attn[tid * 6];
    for (int e = 1; e < 6; ++e) m = fmaxf(m, attn[tid * 6 + e]);
    float ex[6]; float sum = 0.0f;
    for (int e = 0; e < 6; ++e) { ex[e] = expf(attn[tid * 6 + e] - m); sum += ex[e]; }
    const float inv = 1.0f / sum;
    for (int e = 0; e < 6; ++e) attn[tid * 6 + e] = ex[e] * inv;
  }
  __syncthreads();
  for (int i = tid; i < 288; i += 64) {
    const int c = i / 6, e = i - 6 * (i / 6);
    float s = 0.0f;
#pragma unroll
    for (int d = 0; d < 6; ++d) s += wp[c * 48 + 6 * h + d] * attn[d * 6 + e];
    Mmat[((size_t)b * 48 + c) * 48 + 6 * h + e] = s;
  }
}

// ===========================================================================
// K_e: y[b][c][n] = sum_{c'} M_b[c][c'] * v'[b][c'][n]; 1 px/thread,
// vv[48] in VGPRs (spill-free at launch_bounds(256,4): 48+~16 < 128).
// ===========================================================================
__global__ __launch_bounds__(256, 4) void ke_out(
    const __half* __restrict__ vp_ws, const float* __restrict__ Mmat,
    float* __restrict__ y)
{
  const int b = blockIdx.x >> 8;
  const int n = ((blockIdx.x & 255) << 8) + threadIdx.x;
  const __half* vb = vp_ws + ((size_t)b * 48) * NPIX + n;
  const float* Mb = Mmat + (size_t)b * 2304;
  float vv[48];
#pragma unroll
  for (int c = 0; c < 48; ++c) vv[c] = __half2float(vb[(size_t)c * NPIX]);
  float* yb = y + ((size_t)b * 48) * NPIX + n;
#pragma unroll 4
  for (int c = 0; c < 48; ++c) {
    float s = 0.0f;
#pragma unroll
    for (int cc = 0; cc < 48; ++cc) s = fmaf(Mb[c * 48 + cc], vv[cc], s);
    yb[(size_t)c * NPIX] = s;
  }
}

// ===========================================================================
extern "C" void kernel_launch(void* const* d_in, const int* in_sizes, int n_in,
                              void* d_out, int out_size, void* d_ws, size_t ws_size,
                              hipStream_t stream)
{
  const float* x  = (const float*)d_in[0];
  const float* w1 = (const float*)d_in[1];   // (144,48,1,1)
  const float* wd = (const float*)d_in[2];   // (144,1,3,3)
  const float* wp = (const float*)d_in[3];   // (48,48,1,1)

  __half* qkv = (__half*)d_ws;
  __half* vp  = qkv + QKV_H_SIZE;
  float*  fw  = (float*)((char*)d_ws + F_BYTE_OFF);
  float*  gp   = fw;
  float*  Mmat = fw + GP_SIZE;
  float*  w1t  = Mmat + M_SIZE;

  hipLaunchKernelGGL(kt_w1t,   dim3(1),    dim3(256), 0, stream, w1, w1t);
  hipLaunchKernelGGL(ka_conv1, dim3(2048), dim3(256), 0, stream, x, w1t, qkv);
  hipLaunchKernelGGL(kb_qk,    dim3(2048), dim3(256), 0, stream, qkv, wd, gp);
  hipLaunchKernelGGL(kb_v,     dim3(3072), dim3(256), 0, stream, qkv, wd, vp);
  hipLaunchKernelGGL(kd_attn,  dim3(64),   dim3(64),  0, stream, gp, wp, Mmat);
  hipLaunchKernelGGL(ke_out,   dim3(2048), dim3(256), 0, stream, vp, Mmat, (float*)d_out);
}